// Round 3
// baseline (276.825 us; speedup 1.0000x reference)
//
#include <hip/hip_runtime.h>

// Aggregationlayer: coord = clip(x) + mean_k clip(trans)
//                   h = hh + silu([hh | sum_k ef] @ W1 + b1) @ W2 + b2
// R2: edge streaming via global_load_lds into a wave-private 2-deep LDS ring
//     with counted vmcnt(4) (never drained in-loop) -> ~64KB/CU in flight,
//     latency hidden by depth. hh read directly as A-fragments (no LDS stage);
//     MT=16, LDS 33KB, 4 blocks/CU.

typedef float f32x4 __attribute__((ext_vector_type(4)));
typedef short short8 __attribute__((ext_vector_type(8)));
typedef short short4v __attribute__((ext_vector_type(4)));

#define MT 16          // rows per block
#define KNB 16         // K neighbors
#define HNF 256        // feature width
#define ROWB 1056      // staged row stride (1024 data + 32 pad)
#define CHUNKB (MT * ROWB)          // 16896 B per k-slice chunk
#define W1E (512 * 256)
#define W2E (256 * 256)
#define WS_NEEDED ((size_t)(W1E + W2E) * 2)

typedef __attribute__((address_space(3))) void lds_t;
typedef __attribute__((address_space(1))) const void gmem_t;
#define ASYNC16(g, l) \
  __builtin_amdgcn_global_load_lds((gmem_t*)(g), (lds_t*)(l), 16, 0, 0)

__device__ __forceinline__ short f2bf(float f) {
  unsigned u = __builtin_bit_cast(unsigned, f);
  u += 0x7fffu + ((u >> 16) & 1u);   // round-to-nearest-even
  return (short)(u >> 16);
}

__device__ __forceinline__ float clipf(float v) {
  return fminf(fmaxf(v, -1000.f), 1000.f);
}

// ---- pre-kernel: f32 weights -> bf16 fragment layout -----------------------
// dst[(((k>>5)*256 + col)<<5) + ((k>>3)&3)*8 + (k&7)] = bf16(W[k][col])
__global__ void convw(const float* __restrict__ W1, const float* __restrict__ W2,
                      short* __restrict__ wb) {
  int i = blockIdx.x * 256 + threadIdx.x;
  const float* src; short* dst; int k, col;
  if (i < W1E) { src = W1; dst = wb; k = i >> 8; col = i & 255; }
  else         { int j = i - W1E; src = W2; dst = wb + W1E; k = j >> 8; col = j & 255; }
  short v = f2bf(src[((size_t)k << 8) | col]);
  dst[(((k >> 5) * 256 + col) << 5) + ((k >> 3) & 3) * 8 + (k & 7)] = v;
}

__global__ __launch_bounds__(256, 4) void agg_stream(
    const float* __restrict__ x, const float* __restrict__ trans,
    const float* __restrict__ edge, const float* __restrict__ hh,
    const float* __restrict__ b1, const float* __restrict__ b2,
    const short* __restrict__ wb,
    float* __restrict__ coord_out, float* __restrict__ h_out, int N) {
  // smem: [2][CHUNKB] staging ring. After streaming, buf0 is reused:
  //   ef tile [16][256] bf16 (swizzled) at bytes 0..8191
  //   T  tile [16][256] bf16 (swizzled) at bytes 8192..16383
  __shared__ __align__(16) char smem[2 * CHUNKB];

  const int t = threadIdx.x;
  const int w = t >> 6;        // wave 0..3
  const int lane = t & 63;
  const int r0 = blockIdx.x * MT;

  const int lr = lane >> 4;    // local row 0..3 within this wave's 4 rows
  const int cq = lane & 15;    // col-quad base

  // ---------------- streaming reduce of edge (wave-private rows) ------------
  f32x4 acc[4];
#pragma unroll
  for (int j = 0; j < 4; ++j) acc[j] = (f32x4){0.f, 0.f, 0.f, 0.f};

  const char* eb = (const char*)edge;
  const char* src[4];
#pragma unroll
  for (int sr = 0; sr < 4; ++sr) {
    int grow = r0 + w * 4 + sr;
    int gc = grow < N ? grow : N - 1;   // clamp (only matters for tail blocks)
    // source pre-swizzle: lane byte = (lane*16) ^ (sr<<5); LDS dest is linear
    src[sr] = eb + (size_t)gc * (KNB * HNF * 4) + ((lane * 16) ^ (sr << 5));
  }
  const unsigned ldsb = (unsigned)(w * 4) * ROWB;

  const bool full = (r0 + MT <= N);
  if (full) {
    // prologue: chunk 0
#pragma unroll
    for (int sr = 0; sr < 4; ++sr)
      ASYNC16(src[sr], smem + ldsb + sr * ROWB);
    for (int k = 0; k < KNB; ++k) {
      const unsigned cur = (unsigned)(k & 1) * CHUNKB;
      if (k + 1 < KNB) {
        const unsigned nxt = (unsigned)((k + 1) & 1) * CHUNKB;
#pragma unroll
        for (int sr = 0; sr < 4; ++sr)
          ASYNC16(src[sr] + (size_t)(k + 1) * 1024, smem + nxt + ldsb + sr * ROWB);
        asm volatile("s_waitcnt vmcnt(4)" ::: "memory");   // chunk k done, k+1 in flight
      } else {
        asm volatile("s_waitcnt vmcnt(0)" ::: "memory");
      }
      __builtin_amdgcn_sched_barrier(0);
      const char* rb = smem + cur + ldsb + lr * ROWB;
#pragma unroll
      for (int j = 0; j < 4; ++j)
        acc[j] += *(const f32x4*)(rb + (((cq + 16 * j) * 16) ^ (lr << 5)));
    }
  } else {
    // naive guarded path (tail blocks only; N%16==0 in practice)
    for (int k = 0; k < KNB; ++k) {
#pragma unroll
      for (int sr = 0; sr < 4; ++sr)
        if (r0 + w * 4 + sr < N)
          ASYNC16(src[sr] + (size_t)k * 1024, smem + ldsb + sr * ROWB);
      asm volatile("s_waitcnt vmcnt(0)" ::: "memory");
      __builtin_amdgcn_sched_barrier(0);
      const char* rb = smem + ldsb + lr * ROWB;
#pragma unroll
      for (int j = 0; j < 4; ++j)
        acc[j] += *(const f32x4*)(rb + (((cq + 16 * j) * 16) ^ (lr << 5)));
    }
  }

  // ---------------- ef tile write (bf16, swizzled) ----------------
  __syncthreads();   // all waves done reading staging bufs
  {
    int row = w * 4 + lr;
#pragma unroll
    for (int j = 0; j < 4; ++j) {
      short4v v;
#pragma unroll
      for (int e = 0; e < 4; ++e) v[e] = f2bf(acc[j][e]);
      unsigned off = ((unsigned)(row * 512 + (cq + 16 * j) * 8)) ^ ((row & 7) << 4);
      *(short4v*)(smem + off) = v;
    }
  }
  __syncthreads();

  // ---------------- mat1: T = silu([hh|ef] @ W1 + b1) ----------------
  const int colbase = w * 64;
  const int mrow = lane & 15;       // A row / C col within 16-tile
  const int kslot = lane >> 4;      // k-slot within 32-step
  const short8* wf1 = (const short8*)wb;
  const short8* wf2 = (const short8*)(wb + W1E);

  int arow = r0 + mrow; if (arow >= N) arow = N - 1;
  const float* hrow = hh + (size_t)arow * HNF;

  f32x4 acc1[4];
#pragma unroll
  for (int nt = 0; nt < 4; ++nt) acc1[nt] = (f32x4){0.f, 0.f, 0.f, 0.f};

#pragma unroll 2
  for (int kk = 0; kk < 16; ++kk) {
    short8 a;
    if (kk < 8) {
      int k0 = kk * 32 + kslot * 8;
      f32x4 h0 = *(const f32x4*)(hrow + k0);
      f32x4 h1 = *(const f32x4*)(hrow + k0 + 4);
#pragma unroll
      for (int e = 0; e < 4; ++e) { a[e] = f2bf(h0[e]); a[4 + e] = f2bf(h1[e]); }
    } else {
      int k0 = (kk - 8) * 32 + kslot * 8;
      a = *(const short8*)(smem + (((unsigned)(mrow * 512 + k0 * 2)) ^ ((mrow & 7) << 4)));
    }
    const short8* base = wf1 + ((kk * 256 + colbase + mrow) * 4 + kslot);
#pragma unroll
    for (int nt = 0; nt < 4; ++nt)
      acc1[nt] = __builtin_amdgcn_mfma_f32_16x16x32_bf16(a, base[nt * 64], acc1[nt], 0, 0, 0);
  }

  float b1v[4];
#pragma unroll
  for (int nt = 0; nt < 4; ++nt) b1v[nt] = b1[colbase + nt * 16 + mrow];

  // silu + T write (region 8192.. is disjoint from ef region -> no barrier)
#pragma unroll
  for (int nt = 0; nt < 4; ++nt)
#pragma unroll
    for (int r = 0; r < 4; ++r) {
      float v = acc1[nt][r] + b1v[nt];
      v = v / (1.f + __expf(-v));
      int row = kslot * 4 + r;
      int col = colbase + nt * 16 + mrow;
      unsigned off = 8192 + (((unsigned)(row * 512 + col * 2)) ^ ((row & 7) << 4));
      *(short*)(smem + off) = f2bf(v);
    }
  __syncthreads();

  // ---------------- mat2: h = T @ W2 + b2 + hh ----------------
  f32x4 acc2[4];
#pragma unroll
  for (int nt = 0; nt < 4; ++nt) acc2[nt] = (f32x4){0.f, 0.f, 0.f, 0.f};

#pragma unroll 2
  for (int kk = 0; kk < 8; ++kk) {
    int k0 = kk * 32 + kslot * 8;
    short8 a = *(const short8*)(smem + 8192 + (((unsigned)(mrow * 512 + k0 * 2)) ^ ((mrow & 7) << 4)));
    const short8* base = wf2 + ((kk * 256 + colbase + mrow) * 4 + kslot);
#pragma unroll
    for (int nt = 0; nt < 4; ++nt)
      acc2[nt] = __builtin_amdgcn_mfma_f32_16x16x32_bf16(a, base[nt * 64], acc2[nt], 0, 0, 0);
  }

#pragma unroll
  for (int nt = 0; nt < 4; ++nt) {
    int col = colbase + nt * 16 + mrow;
    float bv = b2[col];
#pragma unroll
    for (int r = 0; r < 4; ++r) {
      int row = kslot * 4 + r;
      int grow = r0 + row;
      if (grow < N) {
        size_t idx = (size_t)grow * HNF + col;
        float res = acc2[nt][r] + bv + hh[idx];   // hh L1/L2-hot from mat1
        __builtin_nontemporal_store(res, &h_out[idx]);
      }
    }
  }

  // ---------------- coord (f32 exact), tail work ----------------
  if (lane < 4) {
    int grow = r0 + w * 4 + lane;
    if (grow < N) {
      float cx[3], s[3];
#pragma unroll
      for (int d = 0; d < 3; ++d) { cx[d] = clipf(x[(size_t)grow * 3 + d]); s[d] = 0.f; }
      const float* tp = trans + (size_t)grow * 48;
#pragma unroll
      for (int q = 0; q < 12; ++q) {
        f32x4 v = *(const f32x4*)(tp + q * 4);
#pragma unroll
        for (int e = 0; e < 4; ++e) s[(q * 4 + e) % 3] += clipf(v[e]);
      }
#pragma unroll
      for (int d = 0; d < 3; ++d)
        coord_out[(size_t)grow * 3 + d] = cx[d] + s[d] * (1.f / 16.f);
    }
  }
}

// ---------------- fallback (ws too small): R1 kernel, inline weight cvt -----
__device__ __forceinline__ short8 load_wfrag(const float* __restrict__ W, int k0, int col) {
  short8 r;
#pragma unroll
  for (int j = 0; j < 8; ++j) r[j] = f2bf(W[(size_t)(k0 + j) * 256 + col]);
  return r;
}

__global__ __launch_bounds__(256, 4) void agg_fallback(
    const float* __restrict__ x, const float* __restrict__ trans,
    const float* __restrict__ edge, const float* __restrict__ hh,
    const float* __restrict__ W1, const float* __restrict__ b1,
    const float* __restrict__ W2, const float* __restrict__ b2,
    float* __restrict__ coord_out, float* __restrict__ h_out, int N) {
  __shared__ __align__(16) char smem[32 * 512 * 2];
  const int t = threadIdx.x, w = t >> 6, lane = t & 63;
  const int r0 = blockIdx.x * 32;
  if (lane < 8) {
    int grow = r0 + w * 8 + lane;
    if (grow < N) {
      float cx[3], s[3];
#pragma unroll
      for (int d = 0; d < 3; ++d) { cx[d] = clipf(x[(size_t)grow * 3 + d]); s[d] = 0.f; }
      const float* tp = trans + (size_t)grow * 48;
#pragma unroll
      for (int q = 0; q < 12; ++q) {
        f32x4 v = *(const f32x4*)(tp + q * 4);
#pragma unroll
        for (int e = 0; e < 4; ++e) s[(q * 4 + e) % 3] += clipf(v[e]);
      }
#pragma unroll
      for (int d = 0; d < 3; ++d)
        coord_out[(size_t)grow * 3 + d] = cx[d] + s[d] * (1.f / 16.f);
    }
  }
#pragma unroll
  for (int i0 = 0; i0 < 32; i0 += 4) {
    int row = i0 + w, grow = r0 + row;
    f32x4 ef = {0.f, 0.f, 0.f, 0.f}, hv = {0.f, 0.f, 0.f, 0.f};
    if (grow < N) {
      const float* ep = edge + (size_t)grow * (16 * 256) + lane * 4;
#pragma unroll
      for (int k = 0; k < 16; ++k) ef += *(const f32x4*)(ep + k * 256);
      hv = *(const f32x4*)(hh + (size_t)grow * 256 + lane * 4);
    }
    short4v hb, ebv;
#pragma unroll
    for (int j = 0; j < 4; ++j) { hb[j] = f2bf(hv[j]); ebv[j] = f2bf(ef[j]); }
    int sw = (row & 7) << 4;
    *(short4v*)(smem + ((row * 1024 + lane * 8) ^ sw)) = hb;
    *(short4v*)(smem + ((row * 1024 + 512 + lane * 8) ^ sw)) = ebv;
  }
  __syncthreads();
  const int colbase = w * 64, mrow = lane & 15, kgrp = (lane >> 4) * 8, ncol = lane & 15;
  f32x4 acc1[2][4];
#pragma unroll
  for (int mt = 0; mt < 2; ++mt)
#pragma unroll
    for (int nt = 0; nt < 4; ++nt) acc1[mt][nt] = (f32x4){0.f, 0.f, 0.f, 0.f};
#pragma unroll 2
  for (int kk = 0; kk < 16; ++kk) {
    int k0 = kk * 32 + kgrp, swa = (mrow & 7) << 4;
    short8 a0 = *(const short8*)(smem + ((mrow * 1024 + k0 * 2) ^ swa));
    short8 a1 = *(const short8*)(smem + (((16 + mrow) * 1024 + k0 * 2) ^ swa));
#pragma unroll
    for (int nt = 0; nt < 4; ++nt) {
      short8 bfr = load_wfrag(W1, k0, colbase + nt * 16 + ncol);
      acc1[0][nt] = __builtin_amdgcn_mfma_f32_16x16x32_bf16(a0, bfr, acc1[0][nt], 0, 0, 0);
      acc1[1][nt] = __builtin_amdgcn_mfma_f32_16x16x32_bf16(a1, bfr, acc1[1][nt], 0, 0, 0);
    }
  }
  float b1v[4];
#pragma unroll
  for (int nt = 0; nt < 4; ++nt) b1v[nt] = b1[colbase + nt * 16 + ncol];
  __syncthreads();
#pragma unroll
  for (int mt = 0; mt < 2; ++mt)
#pragma unroll
    for (int nt = 0; nt < 4; ++nt)
#pragma unroll
      for (int r = 0; r < 4; ++r) {
        float v = acc1[mt][nt][r] + b1v[nt];
        v = v / (1.f + __expf(-v));
        int row = mt * 16 + (lane >> 4) * 4 + r, col = colbase + nt * 16 + ncol;
        *(short*)(smem + ((row * 512 + col * 2) ^ ((row & 7) << 4))) = f2bf(v);
      }
  __syncthreads();
  f32x4 acc2[2][4];
#pragma unroll
  for (int mt = 0; mt < 2; ++mt)
#pragma unroll
    for (int nt = 0; nt < 4; ++nt) acc2[mt][nt] = (f32x4){0.f, 0.f, 0.f, 0.f};
#pragma unroll 2
  for (int kk = 0; kk < 8; ++kk) {
    int k0 = kk * 32 + kgrp, swa = (mrow & 7) << 4;
    short8 a0 = *(const short8*)(smem + ((mrow * 512 + k0 * 2) ^ swa));
    short8 a1 = *(const short8*)(smem + (((16 + mrow) * 512 + k0 * 2) ^ swa));
#pragma unroll
    for (int nt = 0; nt < 4; ++nt) {
      short8 bfr = load_wfrag(W2, k0, colbase + nt * 16 + ncol);
      acc2[0][nt] = __builtin_amdgcn_mfma_f32_16x16x32_bf16(a0, bfr, acc2[0][nt], 0, 0, 0);
      acc2[1][nt] = __builtin_amdgcn_mfma_f32_16x16x32_bf16(a1, bfr, acc2[1][nt], 0, 0, 0);
    }
  }
#pragma unroll
  for (int mt = 0; mt < 2; ++mt)
#pragma unroll
    for (int nt = 0; nt < 4; ++nt) {
      int col = colbase + nt * 16 + ncol;
      float bv = b2[col];
#pragma unroll
      for (int r = 0; r < 4; ++r) {
        int row = mt * 16 + (lane >> 4) * 4 + r, grow = r0 + row;
        if (grow < N) {
          size_t idx = (size_t)grow * 256 + col;
          h_out[idx] = acc2[mt][nt][r] + bv + hh[idx];
        }
      }
    }
}

extern "C" void kernel_launch(void* const* d_in, const int* in_sizes, int n_in,
                              void* d_out, int out_size, void* d_ws, size_t ws_size,
                              hipStream_t stream) {
  const float* x     = (const float*)d_in[0];
  const float* trans = (const float*)d_in[1];
  const float* edge  = (const float*)d_in[2];
  const float* hh    = (const float*)d_in[3];
  const float* W1    = (const float*)d_in[4];
  const float* b1    = (const float*)d_in[5];
  const float* W2    = (const float*)d_in[6];
  const float* b2    = (const float*)d_in[7];

  int N = in_sizes[0] / 3;
  float* coord_out = (float*)d_out;
  float* h_out = coord_out + (size_t)N * 3;

  if (ws_size >= WS_NEEDED) {
    short* wb = (short*)d_ws;
    convw<<<(W1E + W2E) / 256, 256, 0, stream>>>(W1, W2, wb);
    int grid = (N + MT - 1) / MT;
    agg_stream<<<grid, 256, 0, stream>>>(x, trans, edge, hh, b1, b2, wb,
                                         coord_out, h_out, N);
  } else {
    int grid = (N + 31) / 32;
    agg_fallback<<<grid, 256, 0, stream>>>(x, trans, edge, hh, W1, b1, W2, b2,
                                           coord_out, h_out, N);
  }
}

// Round 4
// 253.551 us; speedup vs baseline: 1.0918x; 1.0918x over previous
//
#include <hip/hip_runtime.h>

// Aggregationlayer: coord = clip(x) + mean_k clip(trans)
//                   h = hh + silu([hh | sum_k ef] @ W1 + b1) @ W2 + b2
// R3: two-kernel split. K1 = pure streaming reduce (no LDS/barriers, max
//     read BW) writing bf16 ef to d_ws (L2/L3-resident) + coord. K2 = MLP,
//     reading ef/hh directly as MFMA A-fragments (no staging), weights in
//     pre-converted bf16 fragment layout. Tiered fallback to proven R1 path.

typedef float f32x4 __attribute__((ext_vector_type(4)));
typedef short short8 __attribute__((ext_vector_type(8)));
typedef short short4v __attribute__((ext_vector_type(4)));

#define KNB 16
#define HNF 256
#define W1E (512 * 256)
#define W2E (256 * 256)
#define WB_BYTES ((size_t)(W1E + W2E) * 2)   // 393216, 256-aligned
#define EF_OFF WB_BYTES

__device__ __forceinline__ short f2bf(float f) {
  unsigned u = __builtin_bit_cast(unsigned, f);
  u += 0x7fffu + ((u >> 16) & 1u);   // round-to-nearest-even
  return (short)(u >> 16);
}

__device__ __forceinline__ float clipf(float v) {
  return fminf(fmaxf(v, -1000.f), 1000.f);
}

__device__ __forceinline__ f32x4 ldnt4(const float* p) {
  return __builtin_nontemporal_load((const f32x4*)p);
}

// ---- pre-kernel: f32 weights -> bf16 fragment layout -----------------------
// dst[(((k>>5)*256 + col)<<5) + ((k>>3)&3)*8 + (k&7)] = bf16(W[k][col])
__global__ void convw(const float* __restrict__ W1, const float* __restrict__ W2,
                      short* __restrict__ wb) {
  int i = blockIdx.x * 256 + threadIdx.x;
  const float* src; short* dst; int k, col;
  if (i < W1E) { src = W1; dst = wb; k = i >> 8; col = i & 255; }
  else         { int j = i - W1E; src = W2; dst = wb + W1E; k = j >> 8; col = j & 255; }
  short v = f2bf(src[((size_t)k << 8) | col]);
  dst[(((k >> 5) * 256 + col) << 5) + ((k >> 3) & 3) * 8 + (k & 7)] = v;
}

// ---- K1: pure streaming reduce + coord -------------------------------------
// blocks [0,nbE): 16 rows each, wave w owns rows 4w..4w+3, lane owns 4 cols.
// blocks [nbE,..): coord, one row per thread.
__global__ __launch_bounds__(256, 4) void k1_stream(
    const float* __restrict__ edge, const float* __restrict__ x,
    const float* __restrict__ trans, short* __restrict__ efb,
    float* __restrict__ coord_out, int N, int nbE) {
  const int b = blockIdx.x;
  const int t = threadIdx.x;
  if (b < nbE) {
    const int w = t >> 6, lane = t & 63;
    const int r0 = b * 16 + w * 4;
#pragma unroll
    for (int rr = 0; rr < 4; ++rr) {
      int grow = r0 + rr;
      if (grow < N) {
        const float* ep = edge + (size_t)grow * (KNB * HNF) + lane * 4;
        f32x4 acc = {0.f, 0.f, 0.f, 0.f};
#pragma unroll
        for (int k = 0; k < KNB; ++k) acc += ldnt4(ep + k * HNF);
        short4v v;
#pragma unroll
        for (int e = 0; e < 4; ++e) v[e] = f2bf(acc[e]);
        *(short4v*)(efb + (size_t)grow * HNF + lane * 4) = v;   // regular store: L2/L3-resident
      }
    }
  } else {
    int row = (b - nbE) * 256 + t;
    if (row < N) {
      float cx[3], s[3];
#pragma unroll
      for (int d = 0; d < 3; ++d) { cx[d] = clipf(x[(size_t)row * 3 + d]); s[d] = 0.f; }
      const float* tp = trans + (size_t)row * 48;
#pragma unroll
      for (int q = 0; q < 12; ++q) {
        f32x4 v = *(const f32x4*)(tp + q * 4);
#pragma unroll
        for (int e = 0; e < 4; ++e) s[(q * 4 + e) % 3] += clipf(v[e]);
      }
#pragma unroll
      for (int d = 0; d < 3; ++d)
        coord_out[(size_t)row * 3 + d] = cx[d] + s[d] * (1.f / 16.f);
    }
  }
}

// ---- K2: MLP. 32 rows/block, 4 waves x 64 cols, 2 row-groups/wave ---------
__global__ __launch_bounds__(256, 4) void k2_mlp(
    const float* __restrict__ hh, const float* __restrict__ b1,
    const float* __restrict__ b2, const short* __restrict__ wb,
    const short* __restrict__ efb, float* __restrict__ h_out, int N) {
  __shared__ __align__(16) char smem[32 * 512];   // T tile [32][256] bf16, swizzled

  const int t = threadIdx.x;
  const int w = t >> 6, lane = t & 63;
  const int r0 = blockIdx.x * 32;
  const int colbase = w * 64;
  const int mrow = lane & 15;    // A row / C col within 16-tile
  const int kslot = lane >> 4;   // k-slot within 32-step

  const short8* wf1 = (const short8*)wb;
  const short8* wf2 = (const short8*)(wb + W1E);

  const float* hrow[2];
  const short* erow[2];
#pragma unroll
  for (int mt = 0; mt < 2; ++mt) {
    int ar = r0 + mt * 16 + mrow;
    if (ar >= N) ar = N - 1;
    hrow[mt] = hh + (size_t)ar * HNF;
    erow[mt] = efb + (size_t)ar * HNF;
  }

  // ---------------- mat1: T = silu([hh|ef] @ W1 + b1) ----------------
  f32x4 acc1[2][4];
#pragma unroll
  for (int mt = 0; mt < 2; ++mt)
#pragma unroll
    for (int nt = 0; nt < 4; ++nt) acc1[mt][nt] = (f32x4){0.f, 0.f, 0.f, 0.f};

#pragma unroll 2
  for (int kk = 0; kk < 16; ++kk) {
    short8 a[2];
    if (kk < 8) {
      int k0 = kk * 32 + kslot * 8;
#pragma unroll
      for (int mt = 0; mt < 2; ++mt) {
        f32x4 h0 = *(const f32x4*)(hrow[mt] + k0);
        f32x4 h1 = *(const f32x4*)(hrow[mt] + k0 + 4);
#pragma unroll
        for (int e = 0; e < 4; ++e) { a[mt][e] = f2bf(h0[e]); a[mt][4 + e] = f2bf(h1[e]); }
      }
    } else {
      int k0 = (kk - 8) * 32 + kslot * 8;
#pragma unroll
      for (int mt = 0; mt < 2; ++mt)
        a[mt] = *(const short8*)(erow[mt] + k0);
    }
    const short8* base = wf1 + ((kk * 256 + colbase + mrow) * 4 + kslot);
#pragma unroll
    for (int nt = 0; nt < 4; ++nt) {
      short8 bw = base[nt * 64];
      acc1[0][nt] = __builtin_amdgcn_mfma_f32_16x16x32_bf16(a[0], bw, acc1[0][nt], 0, 0, 0);
      acc1[1][nt] = __builtin_amdgcn_mfma_f32_16x16x32_bf16(a[1], bw, acc1[1][nt], 0, 0, 0);
    }
  }

  float b1v[4];
#pragma unroll
  for (int nt = 0; nt < 4; ++nt) b1v[nt] = b1[colbase + nt * 16 + mrow];

  // silu + T write (bf16, swizzled). C/D: row=(lane>>4)*4+reg (+mt*16), col=lane&15
#pragma unroll
  for (int mt = 0; mt < 2; ++mt)
#pragma unroll
    for (int nt = 0; nt < 4; ++nt)
#pragma unroll
      for (int r = 0; r < 4; ++r) {
        float v = acc1[mt][nt][r] + b1v[nt];
        v = v / (1.f + __expf(-v));
        int row = mt * 16 + kslot * 4 + r;
        int col = colbase + nt * 16 + mrow;
        unsigned off = ((unsigned)(row * 512 + col * 2)) ^ ((row & 7) << 4);
        *(short*)(smem + off) = f2bf(v);
      }
  __syncthreads();

  // ---------------- mat2: h = T @ W2 + b2 + hh ----------------
  f32x4 acc2[2][4];
#pragma unroll
  for (int mt = 0; mt < 2; ++mt)
#pragma unroll
    for (int nt = 0; nt < 4; ++nt) acc2[mt][nt] = (f32x4){0.f, 0.f, 0.f, 0.f};

#pragma unroll 2
  for (int kk = 0; kk < 8; ++kk) {
    int k0 = kk * 32 + kslot * 8;
    const short8* base = wf2 + ((kk * 256 + colbase + mrow) * 4 + kslot);
#pragma unroll
    for (int mt = 0; mt < 2; ++mt) {
      int arow = mt * 16 + mrow;
      short8 a = *(const short8*)(smem + (((unsigned)(arow * 512 + k0 * 2)) ^ ((arow & 7) << 4)));
#pragma unroll
      for (int nt = 0; nt < 4; ++nt)
        acc2[mt][nt] = __builtin_amdgcn_mfma_f32_16x16x32_bf16(a, base[nt * 64], acc2[mt][nt], 0, 0, 0);
    }
  }

#pragma unroll
  for (int nt = 0; nt < 4; ++nt) {
    int col = colbase + nt * 16 + mrow;
    float bv = b2[col];
#pragma unroll
    for (int mt = 0; mt < 2; ++mt)
#pragma unroll
      for (int r = 0; r < 4; ++r) {
        int row = mt * 16 + kslot * 4 + r;
        int grow = r0 + row;
        if (grow < N) {
          size_t idx = (size_t)grow * HNF + col;
          float res = acc2[mt][nt][r] + bv + hh[idx];   // hh L1-hot from mat1
          __builtin_nontemporal_store(res, &h_out[idx]);
        }
      }
  }
}

// ---- fused fallback (proven R1 structure), PRE = weights pre-converted -----
__device__ __forceinline__ short8 load_wfrag(const float* __restrict__ W, int k0, int col) {
  short8 r;
#pragma unroll
  for (int j = 0; j < 8; ++j) r[j] = f2bf(W[(size_t)(k0 + j) * 256 + col]);
  return r;
}

template <bool PRE>
__global__ __launch_bounds__(256, 4) void agg_fused(
    const float* __restrict__ x, const float* __restrict__ trans,
    const float* __restrict__ edge, const float* __restrict__ hh,
    const float* __restrict__ W1, const float* __restrict__ b1,
    const float* __restrict__ W2, const float* __restrict__ b2,
    const short* __restrict__ wb,
    float* __restrict__ coord_out, float* __restrict__ h_out, int N) {
  __shared__ __align__(16) char smem[32 * 512 * 2];
  const int t = threadIdx.x, w = t >> 6, lane = t & 63;
  const int r0 = blockIdx.x * 32;
  if (lane < 8) {
    int grow = r0 + w * 8 + lane;
    if (grow < N) {
      float cx[3], s[3];
#pragma unroll
      for (int d = 0; d < 3; ++d) { cx[d] = clipf(x[(size_t)grow * 3 + d]); s[d] = 0.f; }
      const float* tp = trans + (size_t)grow * 48;
#pragma unroll
      for (int q = 0; q < 12; ++q) {
        f32x4 v = *(const f32x4*)(tp + q * 4);
#pragma unroll
        for (int e = 0; e < 4; ++e) s[(q * 4 + e) % 3] += clipf(v[e]);
      }
#pragma unroll
      for (int d = 0; d < 3; ++d)
        coord_out[(size_t)grow * 3 + d] = cx[d] + s[d] * (1.f / 16.f);
    }
  }
#pragma unroll
  for (int i0 = 0; i0 < 32; i0 += 4) {
    int row = i0 + w, grow = r0 + row;
    f32x4 ef = {0.f, 0.f, 0.f, 0.f}, hv = {0.f, 0.f, 0.f, 0.f};
    if (grow < N) {
      const float* ep = edge + (size_t)grow * (16 * 256) + lane * 4;
#pragma unroll
      for (int k = 0; k < 16; ++k) ef += ldnt4(ep + k * 256);
      hv = *(const f32x4*)(hh + (size_t)grow * 256 + lane * 4);
    }
    short4v hb, ebv;
#pragma unroll
    for (int j = 0; j < 4; ++j) { hb[j] = f2bf(hv[j]); ebv[j] = f2bf(ef[j]); }
    int sw = (row & 7) << 4;
    *(short4v*)(smem + ((row * 1024 + lane * 8) ^ sw)) = hb;
    *(short4v*)(smem + ((row * 1024 + 512 + lane * 8) ^ sw)) = ebv;
  }
  __syncthreads();
  const int colbase = w * 64, mrow = lane & 15, kslot = lane >> 4, kgrp = kslot * 8;
  const short8* wf1 = (const short8*)wb;
  const short8* wf2 = (const short8*)(wb + W1E);
  f32x4 acc1[2][4];
#pragma unroll
  for (int mt = 0; mt < 2; ++mt)
#pragma unroll
    for (int nt = 0; nt < 4; ++nt) acc1[mt][nt] = (f32x4){0.f, 0.f, 0.f, 0.f};
#pragma unroll 2
  for (int kk = 0; kk < 16; ++kk) {
    int k0 = kk * 32 + kgrp, swa = (mrow & 7) << 4;
    short8 a0 = *(const short8*)(smem + ((mrow * 1024 + k0 * 2) ^ swa));
    short8 a1 = *(const short8*)(smem + (((16 + mrow) * 1024 + k0 * 2) ^ swa));
#pragma unroll
    for (int nt = 0; nt < 4; ++nt) {
      short8 bw;
      if constexpr (PRE) bw = wf1[(kk * 256 + colbase + mrow) * 4 + kslot + nt * 64];
      else bw = load_wfrag(W1, k0, colbase + nt * 16 + mrow);
      acc1[0][nt] = __builtin_amdgcn_mfma_f32_16x16x32_bf16(a0, bw, acc1[0][nt], 0, 0, 0);
      acc1[1][nt] = __builtin_amdgcn_mfma_f32_16x16x32_bf16(a1, bw, acc1[1][nt], 0, 0, 0);
    }
  }
  float b1v[4];
#pragma unroll
  for (int nt = 0; nt < 4; ++nt) b1v[nt] = b1[colbase + nt * 16 + mrow];
  __syncthreads();
#pragma unroll
  for (int mt = 0; mt < 2; ++mt)
#pragma unroll
    for (int nt = 0; nt < 4; ++nt)
#pragma unroll
      for (int r = 0; r < 4; ++r) {
        float v = acc1[mt][nt][r] + b1v[nt];
        v = v / (1.f + __expf(-v));
        int row = mt * 16 + kslot * 4 + r, col = colbase + nt * 16 + mrow;
        *(short*)(smem + ((row * 512 + col * 2) ^ ((row & 7) << 4))) = f2bf(v);
      }
  __syncthreads();
  f32x4 acc2[2][4];
#pragma unroll
  for (int mt = 0; mt < 2; ++mt)
#pragma unroll
    for (int nt = 0; nt < 4; ++nt) acc2[mt][nt] = (f32x4){0.f, 0.f, 0.f, 0.f};
#pragma unroll 2
  for (int kk = 0; kk < 8; ++kk) {
    int k0 = kk * 32 + kgrp;
#pragma unroll
    for (int mt = 0; mt < 2; ++mt) {
      int arow = mt * 16 + mrow;
      short8 a = *(const short8*)(smem + ((arow * 512 + k0 * 2) ^ ((arow & 7) << 4)));
#pragma unroll
      for (int nt = 0; nt < 4; ++nt) {
        short8 bw;
        if constexpr (PRE) bw = wf2[(kk * 256 + colbase + mrow) * 4 + kslot + nt * 64];
        else bw = load_wfrag(W2, k0, colbase + nt * 16 + mrow);
        acc2[mt][nt] = __builtin_amdgcn_mfma_f32_16x16x32_bf16(a, bw, acc2[mt][nt], 0, 0, 0);
      }
    }
  }
#pragma unroll
  for (int mt = 0; mt < 2; ++mt)
#pragma unroll
    for (int nt = 0; nt < 4; ++nt) {
      int col = colbase + nt * 16 + mrow;
      float bv = b2[col];
#pragma unroll
      for (int r = 0; r < 4; ++r) {
        int row = mt * 16 + kslot * 4 + r, grow = r0 + row;
        if (grow < N) {
          size_t idx = (size_t)grow * 256 + col;
          h_out[idx] = acc2[mt][nt][r] + bv + hh[idx];
        }
      }
    }
}

extern "C" void kernel_launch(void* const* d_in, const int* in_sizes, int n_in,
                              void* d_out, int out_size, void* d_ws, size_t ws_size,
                              hipStream_t stream) {
  const float* x     = (const float*)d_in[0];
  const float* trans = (const float*)d_in[1];
  const float* edge  = (const float*)d_in[2];
  const float* hh    = (const float*)d_in[3];
  const float* W1    = (const float*)d_in[4];
  const float* b1    = (const float*)d_in[5];
  const float* W2    = (const float*)d_in[6];
  const float* b2    = (const float*)d_in[7];

  int N = in_sizes[0] / 3;
  float* coord_out = (float*)d_out;
  float* h_out = coord_out + (size_t)N * 3;

  size_t ws_full = EF_OFF + (size_t)N * HNF * 2;

  if (ws_size >= ws_full) {
    short* wb = (short*)d_ws;
    short* efb = (short*)((char*)d_ws + EF_OFF);
    convw<<<(W1E + W2E) / 256, 256, 0, stream>>>(W1, W2, wb);
    int nbE = (N + 15) / 16;
    int nbC = (N + 255) / 256;
    k1_stream<<<nbE + nbC, 256, 0, stream>>>(edge, x, trans, efb, coord_out, N, nbE);
    k2_mlp<<<(N + 31) / 32, 256, 0, stream>>>(hh, b1, b2, wb, efb, h_out, N);
  } else if (ws_size >= WB_BYTES) {
    short* wb = (short*)d_ws;
    convw<<<(W1E + W2E) / 256, 256, 0, stream>>>(W1, W2, wb);
    agg_fused<true><<<(N + 31) / 32, 256, 0, stream>>>(x, trans, edge, hh, W1, b1, W2, b2,
                                                       wb, coord_out, h_out, N);
  } else {
    agg_fused<false><<<(N + 31) / 32, 256, 0, stream>>>(x, trans, edge, hh, W1, b1, W2, b2,
                                                        nullptr, coord_out, h_out, N);
  }
}

// Round 5
// 213.864 us; speedup vs baseline: 1.2944x; 1.1856x over previous
//
#include <hip/hip_runtime.h>

// Aggregationlayer: coord = clip(x) + mean_k clip(trans)
//                   h = hh + silu([hh | sum_k ef] @ W1 + b1) @ W2 + b2
// R4: back to fused R1 skeleton (best: 199.5us). Slimmed for occupancy:
//     - hh NOT staged in LDS; read directly as mat1 A-fragments (L1 reuse x4)
//     - LDS 16KB: ef tile [32][256]bf16 swizzled, reused for T after barrier
//     - __launch_bounds__(256,5): 5 blocks/CU (20 waves) vs 4 (16 waves)
//     - paired-row streaming: 32 independent loads, 2 acc chains per wave

typedef float f32x4 __attribute__((ext_vector_type(4)));
typedef short short8 __attribute__((ext_vector_type(8)));
typedef short short4v __attribute__((ext_vector_type(4)));

#define KNB 16
#define HNF 256
#define W1E (512 * 256)
#define W2E (256 * 256)
#define WB_BYTES ((size_t)(W1E + W2E) * 2)

__device__ __forceinline__ short f2bf(float f) {
  unsigned u = __builtin_bit_cast(unsigned, f);
  u += 0x7fffu + ((u >> 16) & 1u);   // round-to-nearest-even
  return (short)(u >> 16);
}

__device__ __forceinline__ float clipf(float v) {
  return fminf(fmaxf(v, -1000.f), 1000.f);
}

__device__ __forceinline__ f32x4 ldnt4(const float* p) {
  return __builtin_nontemporal_load((const f32x4*)p);
}

// ---- pre-kernel: f32 weights -> bf16 fragment layout -----------------------
// dst[(((k>>5)*256 + col)<<5) + ((k>>3)&3)*8 + (k&7)] = bf16(W[k][col])
__global__ void convw(const float* __restrict__ W1, const float* __restrict__ W2,
                      short* __restrict__ wb) {
  int i = blockIdx.x * 256 + threadIdx.x;
  const float* src; short* dst; int k, col;
  if (i < W1E) { src = W1; dst = wb; k = i >> 8; col = i & 255; }
  else         { int j = i - W1E; src = W2; dst = wb + W1E; k = j >> 8; col = j & 255; }
  short v = f2bf(src[((size_t)k << 8) | col]);
  dst[(((k >> 5) * 256 + col) << 5) + ((k >> 3) & 3) * 8 + (k & 7)] = v;
}

// ---- fused main kernel -----------------------------------------------------
__global__ __launch_bounds__(256, 5) void agg_slim(
    const float* __restrict__ x, const float* __restrict__ trans,
    const float* __restrict__ edge, const float* __restrict__ hh,
    const float* __restrict__ b1, const float* __restrict__ b2,
    const short* __restrict__ wb,
    float* __restrict__ coord_out, float* __restrict__ h_out, int N) {
  // 16 KB: ef tile [32][256] bf16 swizzled (row stride 512B); reused for T.
  __shared__ __align__(16) char smem[32 * 512];

  const int t = threadIdx.x;
  const int w = t >> 6, lane = t & 63;
  const int r0 = blockIdx.x * 32;

  // ---------------- coord (f32 exact) ----------------
  if (lane < 8) {
    int grow = r0 + w * 8 + lane;
    if (grow < N) {
      float cx[3], s[3];
#pragma unroll
      for (int d = 0; d < 3; ++d) { cx[d] = clipf(x[(size_t)grow * 3 + d]); s[d] = 0.f; }
      const float* tp = trans + (size_t)grow * 48;
#pragma unroll
      for (int q = 0; q < 12; ++q) {
        f32x4 v = *(const f32x4*)(tp + q * 4);
#pragma unroll
        for (int e = 0; e < 4; ++e) s[(q * 4 + e) % 3] += clipf(v[e]);
      }
#pragma unroll
      for (int d = 0; d < 3; ++d)
        coord_out[(size_t)grow * 3 + d] = cx[d] + s[d] * (1.f / 16.f);
    }
  }

  // ---------------- stream edge -> ef tile (bf16, swizzled) ----------------
  // wave w owns rows w*8..w*8+7, processed in pairs for ILP (32 loads/2 chains)
#pragma unroll
  for (int rr = 0; rr < 8; rr += 2) {
    int row0 = w * 8 + rr, row1 = row0 + 1;
    int g0 = r0 + row0, g1 = r0 + row1;
    const float* p0 = edge + (size_t)(g0 < N ? g0 : 0) * (KNB * HNF) + lane * 4;
    const float* p1 = edge + (size_t)(g1 < N ? g1 : 0) * (KNB * HNF) + lane * 4;
    f32x4 a0 = {0.f, 0.f, 0.f, 0.f}, a1 = {0.f, 0.f, 0.f, 0.f};
#pragma unroll
    for (int k = 0; k < KNB; ++k) {
      a0 += ldnt4(p0 + k * HNF);
      a1 += ldnt4(p1 + k * HNF);
    }
    if (g0 >= N) a0 = (f32x4){0.f, 0.f, 0.f, 0.f};
    if (g1 >= N) a1 = (f32x4){0.f, 0.f, 0.f, 0.f};
    short4v v0, v1;
#pragma unroll
    for (int e = 0; e < 4; ++e) { v0[e] = f2bf(a0[e]); v1[e] = f2bf(a1[e]); }
    *(short4v*)(smem + (((unsigned)(row0 * 512 + lane * 8)) ^ ((row0 & 7) << 4))) = v0;
    *(short4v*)(smem + (((unsigned)(row1 * 512 + lane * 8)) ^ ((row1 & 7) << 4))) = v1;
  }
  __syncthreads();

  // ---------------- mat1: T = silu([hh|ef] @ W1 + b1) ----------------
  const int colbase = w * 64;
  const int mrow = lane & 15;    // A row / C col within 16-tile
  const int kslot = lane >> 4;   // k-slot within 32-step
  const short8* wf1 = (const short8*)wb;
  const short8* wf2 = (const short8*)(wb + W1E);

  const float* hrow[2];
  {
    int ar0 = r0 + mrow;      if (ar0 >= N) ar0 = N - 1;
    int ar1 = r0 + 16 + mrow; if (ar1 >= N) ar1 = N - 1;
    hrow[0] = hh + (size_t)ar0 * HNF;
    hrow[1] = hh + (size_t)ar1 * HNF;
  }

  f32x4 acc1[2][4];
#pragma unroll
  for (int mt = 0; mt < 2; ++mt)
#pragma unroll
    for (int nt = 0; nt < 4; ++nt) acc1[mt][nt] = (f32x4){0.f, 0.f, 0.f, 0.f};

#pragma unroll 2
  for (int kk = 0; kk < 16; ++kk) {
    short8 a[2];
    if (kk < 8) {
      int k0 = kk * 32 + kslot * 8;
#pragma unroll
      for (int mt = 0; mt < 2; ++mt) {
        f32x4 h0 = *(const f32x4*)(hrow[mt] + k0);
        f32x4 h1 = *(const f32x4*)(hrow[mt] + k0 + 4);
#pragma unroll
        for (int e = 0; e < 4; ++e) { a[mt][e] = f2bf(h0[e]); a[mt][4 + e] = f2bf(h1[e]); }
      }
    } else {
      int k0 = (kk - 8) * 32 + kslot * 8;
#pragma unroll
      for (int mt = 0; mt < 2; ++mt) {
        int row = mt * 16 + mrow;
        a[mt] = *(const short8*)(smem + (((unsigned)(row * 512 + k0 * 2)) ^ ((row & 7) << 4)));
      }
    }
    const short8* base = wf1 + ((kk * 256 + colbase + mrow) * 4 + kslot);
#pragma unroll
    for (int nt = 0; nt < 4; ++nt) {
      short8 bw = base[nt * 64];
      acc1[0][nt] = __builtin_amdgcn_mfma_f32_16x16x32_bf16(a[0], bw, acc1[0][nt], 0, 0, 0);
      acc1[1][nt] = __builtin_amdgcn_mfma_f32_16x16x32_bf16(a[1], bw, acc1[1][nt], 0, 0, 0);
    }
  }

  float b1v[4];
#pragma unroll
  for (int nt = 0; nt < 4; ++nt) b1v[nt] = b1[colbase + nt * 16 + mrow];

  __syncthreads();   // all waves done reading ef; T overwrites same region

  // silu + T write. C/D: row=(lane>>4)*4+reg (+mt*16), col=lane&15
#pragma unroll
  for (int mt = 0; mt < 2; ++mt)
#pragma unroll
    for (int nt = 0; nt < 4; ++nt)
#pragma unroll
      for (int r = 0; r < 4; ++r) {
        float v = acc1[mt][nt][r] + b1v[nt];
        v = v / (1.f + __expf(-v));
        int row = mt * 16 + kslot * 4 + r;
        int col = colbase + nt * 16 + mrow;
        unsigned off = ((unsigned)(row * 512 + col * 2)) ^ ((row & 7) << 4);
        *(short*)(smem + off) = f2bf(v);
      }
  __syncthreads();

  // ---------------- mat2: h = T @ W2 + b2 + hh ----------------
  f32x4 acc2[2][4];
#pragma unroll
  for (int mt = 0; mt < 2; ++mt)
#pragma unroll
    for (int nt = 0; nt < 4; ++nt) acc2[mt][nt] = (f32x4){0.f, 0.f, 0.f, 0.f};

#pragma unroll 2
  for (int kk = 0; kk < 8; ++kk) {
    int k0 = kk * 32 + kslot * 8;
    const short8* base = wf2 + ((kk * 256 + colbase + mrow) * 4 + kslot);
#pragma unroll
    for (int mt = 0; mt < 2; ++mt) {
      int arow = mt * 16 + mrow;
      short8 a = *(const short8*)(smem + (((unsigned)(arow * 512 + k0 * 2)) ^ ((arow & 7) << 4)));
#pragma unroll
      for (int nt = 0; nt < 4; ++nt)
        acc2[mt][nt] = __builtin_amdgcn_mfma_f32_16x16x32_bf16(a, base[nt * 64], acc2[mt][nt], 0, 0, 0);
    }
  }

#pragma unroll
  for (int nt = 0; nt < 4; ++nt) {
    int col = colbase + nt * 16 + mrow;
    float bv = b2[col];
#pragma unroll
    for (int mt = 0; mt < 2; ++mt)
#pragma unroll
      for (int r = 0; r < 4; ++r) {
        int row = mt * 16 + kslot * 4 + r;
        int grow = r0 + row;
        if (grow < N) {
          size_t idx = (size_t)grow * HNF + col;
          float res = acc2[mt][nt][r] + bv + hh[idx];   // L1-hot from mat1
          __builtin_nontemporal_store(res, &h_out[idx]);
        }
      }
  }
}

// ---- fallback (ws too small for wb): inline weight conversion --------------
__device__ __forceinline__ short8 load_wfrag(const float* __restrict__ W, int k0, int col) {
  short8 r;
#pragma unroll
  for (int j = 0; j < 8; ++j) r[j] = f2bf(W[(size_t)(k0 + j) * 256 + col]);
  return r;
}

__global__ __launch_bounds__(256, 4) void agg_fallback(
    const float* __restrict__ x, const float* __restrict__ trans,
    const float* __restrict__ edge, const float* __restrict__ hh,
    const float* __restrict__ W1, const float* __restrict__ b1,
    const float* __restrict__ W2, const float* __restrict__ b2,
    float* __restrict__ coord_out, float* __restrict__ h_out, int N) {
  __shared__ __align__(16) char smem[32 * 512 * 2];
  const int t = threadIdx.x, w = t >> 6, lane = t & 63;
  const int r0 = blockIdx.x * 32;
  if (lane < 8) {
    int grow = r0 + w * 8 + lane;
    if (grow < N) {
      float cx[3], s[3];
#pragma unroll
      for (int d = 0; d < 3; ++d) { cx[d] = clipf(x[(size_t)grow * 3 + d]); s[d] = 0.f; }
      const float* tp = trans + (size_t)grow * 48;
#pragma unroll
      for (int q = 0; q < 12; ++q) {
        f32x4 v = *(const f32x4*)(tp + q * 4);
#pragma unroll
        for (int e = 0; e < 4; ++e) s[(q * 4 + e) % 3] += clipf(v[e]);
      }
#pragma unroll
      for (int d = 0; d < 3; ++d)
        coord_out[(size_t)grow * 3 + d] = cx[d] + s[d] * (1.f / 16.f);
    }
  }
#pragma unroll
  for (int i0 = 0; i0 < 32; i0 += 4) {
    int row = i0 + w, grow = r0 + row;
    f32x4 ef = {0.f, 0.f, 0.f, 0.f}, hv = {0.f, 0.f, 0.f, 0.f};
    if (grow < N) {
      const float* ep = edge + (size_t)grow * (16 * 256) + lane * 4;
#pragma unroll
      for (int k = 0; k < 16; ++k) ef += ldnt4(ep + k * 256);
      hv = *(const f32x4*)(hh + (size_t)grow * 256 + lane * 4);
    }
    short4v hb, ebv;
#pragma unroll
    for (int j = 0; j < 4; ++j) { hb[j] = f2bf(hv[j]); ebv[j] = f2bf(ef[j]); }
    int sw = (row & 7) << 4;
    *(short4v*)(smem + ((row * 1024 + lane * 8) ^ sw)) = hb;
    *(short4v*)(smem + ((row * 1024 + 512 + lane * 8) ^ sw)) = ebv;
  }
  __syncthreads();
  const int colbase = w * 64, mrow = lane & 15, kslot = lane >> 4, kgrp = kslot * 8;
  f32x4 acc1[2][4];
#pragma unroll
  for (int mt = 0; mt < 2; ++mt)
#pragma unroll
    for (int nt = 0; nt < 4; ++nt) acc1[mt][nt] = (f32x4){0.f, 0.f, 0.f, 0.f};
#pragma unroll 2
  for (int kk = 0; kk < 16; ++kk) {
    int k0 = kk * 32 + kgrp, swa = (mrow & 7) << 4;
    short8 a0 = *(const short8*)(smem + ((mrow * 1024 + k0 * 2) ^ swa));
    short8 a1 = *(const short8*)(smem + (((16 + mrow) * 1024 + k0 * 2) ^ swa));
#pragma unroll
    for (int nt = 0; nt < 4; ++nt) {
      short8 bw = load_wfrag(W1, k0, colbase + nt * 16 + mrow);
      acc1[0][nt] = __builtin_amdgcn_mfma_f32_16x16x32_bf16(a0, bw, acc1[0][nt], 0, 0, 0);
      acc1[1][nt] = __builtin_amdgcn_mfma_f32_16x16x32_bf16(a1, bw, acc1[1][nt], 0, 0, 0);
    }
  }
  float b1v[4];
#pragma unroll
  for (int nt = 0; nt < 4; ++nt) b1v[nt] = b1[colbase + nt * 16 + mrow];
  __syncthreads();
#pragma unroll
  for (int mt = 0; mt < 2; ++mt)
#pragma unroll
    for (int nt = 0; nt < 4; ++nt)
#pragma unroll
      for (int r = 0; r < 4; ++r) {
        float v = acc1[mt][nt][r] + b1v[nt];
        v = v / (1.f + __expf(-v));
        int row = mt * 16 + kslot * 4 + r, col = colbase + nt * 16 + mrow;
        *(short*)(smem + ((row * 512 + col * 2) ^ ((row & 7) << 4))) = f2bf(v);
      }
  __syncthreads();
  f32x4 acc2[2][4];
#pragma unroll
  for (int mt = 0; mt < 2; ++mt)
#pragma unroll
    for (int nt = 0; nt < 4; ++nt) acc2[mt][nt] = (f32x4){0.f, 0.f, 0.f, 0.f};
#pragma unroll 2
  for (int kk = 0; kk < 8; ++kk) {
    int k0 = kk * 32 + kgrp;
#pragma unroll
    for (int mt = 0; mt < 2; ++mt) {
      int arow = mt * 16 + mrow;
      short8 a = *(const short8*)(smem + ((arow * 512 + k0 * 2) ^ ((arow & 7) << 4)));
#pragma unroll
      for (int nt = 0; nt < 4; ++nt) {
        short8 bw = load_wfrag(W2, k0, colbase + nt * 16 + mrow);
        acc2[mt][nt] = __builtin_amdgcn_mfma_f32_16x16x32_bf16(a, bw, acc2[mt][nt], 0, 0, 0);
      }
    }
  }
#pragma unroll
  for (int mt = 0; mt < 2; ++mt)
#pragma unroll
    for (int nt = 0; nt < 4; ++nt) {
      int col = colbase + nt * 16 + mrow;
      float bv = b2[col];
#pragma unroll
      for (int r = 0; r < 4; ++r) {
        int row = mt * 16 + kslot * 4 + r, grow = r0 + row;
        if (grow < N) {
          size_t idx = (size_t)grow * 256 + col;
          h_out[idx] = acc2[mt][nt][r] + bv + hh[idx];
        }
      }
    }
}

extern "C" void kernel_launch(void* const* d_in, const int* in_sizes, int n_in,
                              void* d_out, int out_size, void* d_ws, size_t ws_size,
                              hipStream_t stream) {
  const float* x     = (const float*)d_in[0];
  const float* trans = (const float*)d_in[1];
  const float* edge  = (const float*)d_in[2];
  const float* hh    = (const float*)d_in[3];
  const float* W1    = (const float*)d_in[4];
  const float* b1    = (const float*)d_in[5];
  const float* W2    = (const float*)d_in[6];
  const float* b2    = (const float*)d_in[7];

  int N = in_sizes[0] / 3;
  float* coord_out = (float*)d_out;
  float* h_out = coord_out + (size_t)N * 3;
  int grid = (N + 31) / 32;

  if (ws_size >= WB_BYTES) {
    short* wb = (short*)d_ws;
    convw<<<(W1E + W2E) / 256, 256, 0, stream>>>(W1, W2, wb);
    agg_slim<<<grid, 256, 0, stream>>>(x, trans, edge, hh, b1, b2, wb,
                                       coord_out, h_out, N);
  } else {
    agg_fallback<<<grid, 256, 0, stream>>>(x, trans, edge, hh, W1, b1, W2, b2,
                                           coord_out, h_out, N);
  }
}

// Round 6
// 195.401 us; speedup vs baseline: 1.4167x; 1.0945x over previous
//
#include <hip/hip_runtime.h>

// Aggregationlayer: coord = clip(x) + mean_k clip(trans)
//                   h = hh + silu([hh | sum_k ef] @ W1 + b1) @ W2 + b2
// R5 = R1 skeleton (best, 199.5us) + two targeted changes:
//  1) __launch_bounds__(256,5): 5 blocks/CU (LDS 5x32KB = 160KB exact),
//     VGPR cap 102 (phase-wise need ~85) -> 20 streaming waves/CU vs 16.
//  2) residual hh taken from the staged LDS tile (bf16) instead of a second
//     HBM read (-51 MB); T is written into the dead ef half-columns so the
//     hh half stays live for the epilogue.

typedef float f32x4 __attribute__((ext_vector_type(4)));
typedef short short8 __attribute__((ext_vector_type(8)));
typedef short short4v __attribute__((ext_vector_type(4)));

#define KNB 16
#define HNF 256
#define W1E (512 * 256)
#define W2E (256 * 256)
#define WB_BYTES ((size_t)(W1E + W2E) * 2)

__device__ __forceinline__ short f2bf(float f) {
  unsigned u = __builtin_bit_cast(unsigned, f);
  u += 0x7fffu + ((u >> 16) & 1u);   // round-to-nearest-even
  return (short)(u >> 16);
}

__device__ __forceinline__ float bf2f(short s) {
  unsigned u = ((unsigned)(unsigned short)s) << 16;
  return __builtin_bit_cast(float, u);
}

__device__ __forceinline__ float clipf(float v) {
  return fminf(fmaxf(v, -1000.f), 1000.f);
}

__device__ __forceinline__ f32x4 ldnt4(const float* p) {
  return __builtin_nontemporal_load((const f32x4*)p);
}

// ---- pre-kernel: f32 weights -> bf16 fragment layout -----------------------
// dst[(((k>>5)*256 + col)<<5) + ((k>>3)&3)*8 + (k&7)] = bf16(W[k][col])
__global__ void convw(const float* __restrict__ W1, const float* __restrict__ W2,
                      short* __restrict__ wb) {
  int i = blockIdx.x * 256 + threadIdx.x;
  const float* src; short* dst; int k, col;
  if (i < W1E) { src = W1; dst = wb; k = i >> 8; col = i & 255; }
  else         { int j = i - W1E; src = W2; dst = wb + W1E; k = j >> 8; col = j & 255; }
  short v = f2bf(src[((size_t)k << 8) | col]);
  dst[(((k >> 5) * 256 + col) << 5) + ((k >> 3) & 3) * 8 + (k & 7)] = v;
}

// ---- fused main kernel (R1 structure, occupancy 5) --------------------------
__global__ __launch_bounds__(256, 5) void agg_fused5(
    const float* __restrict__ x, const float* __restrict__ trans,
    const float* __restrict__ edge, const float* __restrict__ hh,
    const float* __restrict__ b1, const float* __restrict__ b2,
    const short* __restrict__ wb,
    float* __restrict__ coord_out, float* __restrict__ h_out, int N) {
  // agg tile [32][512] bf16 (row stride 1024B), XOR-swizzled. 32 KB.
  // cols 0..255 = hh (live until epilogue), 256..511 = ef (T overwrites it).
  __shared__ __align__(16) char smem[32 * 1024];

  const int t = threadIdx.x;
  const int w = t >> 6, lane = t & 63;
  const int r0 = blockIdx.x * 32;

  // ---------------- coord (f32 exact) ----------------
  if (lane < 8) {
    int grow = r0 + w * 8 + lane;
    if (grow < N) {
      float cx[3], s[3];
#pragma unroll
      for (int d = 0; d < 3; ++d) { cx[d] = clipf(x[(size_t)grow * 3 + d]); s[d] = 0.f; }
      const float* tp = trans + (size_t)grow * 48;
#pragma unroll
      for (int q = 0; q < 12; ++q) {
        f32x4 v = *(const f32x4*)(tp + q * 4);
#pragma unroll
        for (int e = 0; e < 4; ++e) s[(q * 4 + e) % 3] += clipf(v[e]);
      }
#pragma unroll
      for (int d = 0; d < 3; ++d)
        coord_out[(size_t)grow * 3 + d] = cx[d] + s[d] * (1.f / 16.f);
    }
  }

  // ---------------- stage agg = [hh | sum_k edge] as bf16 ----------------
  // wave w handles row i0+w; 64 lanes cover 256 cols as float4 (R1 pattern).
#pragma unroll
  for (int i0 = 0; i0 < 32; i0 += 4) {
    int row = i0 + w;
    int grow = r0 + row;
    f32x4 ef = {0.f, 0.f, 0.f, 0.f};
    f32x4 hv = {0.f, 0.f, 0.f, 0.f};
    if (grow < N) {
      const float* ep = edge + (size_t)grow * (KNB * HNF) + lane * 4;
#pragma unroll
      for (int k = 0; k < KNB; ++k) ef += ldnt4(ep + k * HNF);   // non-temporal
      hv = *(const f32x4*)(hh + (size_t)grow * HNF + lane * 4);
    }
    short4v hb, eb;
#pragma unroll
    for (int j = 0; j < 4; ++j) { hb[j] = f2bf(hv[j]); eb[j] = f2bf(ef[j]); }
    int sw = (row & 7) << 4;
    *(short4v*)(smem + ((row * 1024 + lane * 8) ^ sw)) = hb;
    *(short4v*)(smem + ((row * 1024 + 512 + lane * 8) ^ sw)) = eb;
  }
  __syncthreads();

  // ---------------- mat1: T = silu([hh|ef] @ W1 + b1) ----------------
  const int colbase = w * 64;
  const int mrow = lane & 15;    // A row / C col within 16-tile
  const int kslot = lane >> 4;   // k-slot within 32-step
  const short8* wf1 = (const short8*)wb;
  const short8* wf2 = (const short8*)(wb + W1E);

  f32x4 acc1[2][4];
#pragma unroll
  for (int mt = 0; mt < 2; ++mt)
#pragma unroll
    for (int nt = 0; nt < 4; ++nt) acc1[mt][nt] = (f32x4){0.f, 0.f, 0.f, 0.f};

#pragma unroll 2
  for (int kk = 0; kk < 16; ++kk) {
    int k0 = kk * 32 + kslot * 8;
    int swa = (mrow & 7) << 4;
    short8 a0 = *(const short8*)(smem + ((mrow * 1024 + k0 * 2) ^ swa));
    short8 a1 = *(const short8*)(smem + (((16 + mrow) * 1024 + k0 * 2) ^ ((mrow & 7) << 4)));
    const short8* base = wf1 + ((kk * 256 + colbase + mrow) * 4 + kslot);
#pragma unroll
    for (int nt = 0; nt < 4; ++nt) {
      short8 bw = base[nt * 64];
      acc1[0][nt] = __builtin_amdgcn_mfma_f32_16x16x32_bf16(a0, bw, acc1[0][nt], 0, 0, 0);
      acc1[1][nt] = __builtin_amdgcn_mfma_f32_16x16x32_bf16(a1, bw, acc1[1][nt], 0, 0, 0);
    }
  }

  float b1v[4];
#pragma unroll
  for (int nt = 0; nt < 4; ++nt) b1v[nt] = b1[colbase + nt * 16 + mrow];

  __syncthreads();   // all waves done reading ef fragments before T overwrites

  // silu + T write into the ef half (bytes row*1024+512..+1023, swizzled).
  // C/D mapping: row=(lane>>4)*4+reg (+mt*16), col=lane&15 (+colbase+nt*16).
#pragma unroll
  for (int mt = 0; mt < 2; ++mt)
#pragma unroll
    for (int nt = 0; nt < 4; ++nt)
#pragma unroll
      for (int r = 0; r < 4; ++r) {
        float v = acc1[mt][nt][r] + b1v[nt];
        v = v / (1.f + __expf(-v));
        int row = mt * 16 + kslot * 4 + r;
        int col = colbase + nt * 16 + mrow;
        unsigned off = ((unsigned)(row * 1024 + 512 + col * 2)) ^ ((row & 7) << 4);
        *(short*)(smem + off) = f2bf(v);
      }
  __syncthreads();

  // ---------------- mat2: h = T @ W2 + b2 + hh(LDS) ----------------
  f32x4 acc2[2][4];
#pragma unroll
  for (int mt = 0; mt < 2; ++mt)
#pragma unroll
    for (int nt = 0; nt < 4; ++nt) acc2[mt][nt] = (f32x4){0.f, 0.f, 0.f, 0.f};

#pragma unroll 2
  for (int kk = 0; kk < 8; ++kk) {
    int k0 = kk * 32 + kslot * 8;
    const short8* base = wf2 + ((kk * 256 + colbase + mrow) * 4 + kslot);
#pragma unroll
    for (int mt = 0; mt < 2; ++mt) {
      int arow = mt * 16 + mrow;
      short8 a = *(const short8*)(smem + (((unsigned)(arow * 1024 + 512 + k0 * 2)) ^ ((arow & 7) << 4)));
#pragma unroll
      for (int nt = 0; nt < 4; ++nt)
        acc2[mt][nt] = __builtin_amdgcn_mfma_f32_16x16x32_bf16(a, base[nt * 64], acc2[mt][nt], 0, 0, 0);
    }
  }

#pragma unroll
  for (int nt = 0; nt < 4; ++nt) {
    int col = colbase + nt * 16 + mrow;
    float bv = b2[col];
#pragma unroll
    for (int mt = 0; mt < 2; ++mt)
#pragma unroll
      for (int r = 0; r < 4; ++r) {
        int row = mt * 16 + kslot * 4 + r;
        int grow = r0 + row;
        if (grow < N) {
          // residual from the staged bf16 hh tile (hh half still intact)
          unsigned hoff = ((unsigned)(row * 1024 + col * 2)) ^ ((row & 7) << 4);
          float hres = bf2f(*(const short*)(smem + hoff));
          size_t idx = (size_t)grow * HNF + col;
          float res = acc2[mt][nt][r] + bv + hres;
          __builtin_nontemporal_store(res, &h_out[idx]);
        }
      }
  }
}

// ---- fallback (ws too small for wb): inline weight conversion --------------
__device__ __forceinline__ short8 load_wfrag(const float* __restrict__ W, int k0, int col) {
  short8 r;
#pragma unroll
  for (int j = 0; j < 8; ++j) r[j] = f2bf(W[(size_t)(k0 + j) * 256 + col]);
  return r;
}

__global__ __launch_bounds__(256, 4) void agg_fallback(
    const float* __restrict__ x, const float* __restrict__ trans,
    const float* __restrict__ edge, const float* __restrict__ hh,
    const float* __restrict__ W1, const float* __restrict__ b1,
    const float* __restrict__ W2, const float* __restrict__ b2,
    float* __restrict__ coord_out, float* __restrict__ h_out, int N) {
  __shared__ __align__(16) char smem[32 * 512 * 2];
  const int t = threadIdx.x, w = t >> 6, lane = t & 63;
  const int r0 = blockIdx.x * 32;
  if (lane < 8) {
    int grow = r0 + w * 8 + lane;
    if (grow < N) {
      float cx[3], s[3];
#pragma unroll
      for (int d = 0; d < 3; ++d) { cx[d] = clipf(x[(size_t)grow * 3 + d]); s[d] = 0.f; }
      const float* tp = trans + (size_t)grow * 48;
#pragma unroll
      for (int q = 0; q < 12; ++q) {
        f32x4 v = *(const f32x4*)(tp + q * 4);
#pragma unroll
        for (int e = 0; e < 4; ++e) s[(q * 4 + e) % 3] += clipf(v[e]);
      }
#pragma unroll
      for (int d = 0; d < 3; ++d)
        coord_out[(size_t)grow * 3 + d] = cx[d] + s[d] * (1.f / 16.f);
    }
  }
#pragma unroll
  for (int i0 = 0; i0 < 32; i0 += 4) {
    int row = i0 + w, grow = r0 + row;
    f32x4 ef = {0.f, 0.f, 0.f, 0.f}, hv = {0.f, 0.f, 0.f, 0.f};
    if (grow < N) {
      const float* ep = edge + (size_t)grow * (16 * 256) + lane * 4;
#pragma unroll
      for (int k = 0; k < 16; ++k) ef += ldnt4(ep + k * 256);
      hv = *(const f32x4*)(hh + (size_t)grow * 256 + lane * 4);
    }
    short4v hb, ebv;
#pragma unroll
    for (int j = 0; j < 4; ++j) { hb[j] = f2bf(hv[j]); ebv[j] = f2bf(ef[j]); }
    int sw = (row & 7) << 4;
    *(short4v*)(smem + ((row * 1024 + lane * 8) ^ sw)) = hb;
    *(short4v*)(smem + ((row * 1024 + 512 + lane * 8) ^ sw)) = ebv;
  }
  __syncthreads();
  const int colbase = w * 64, mrow = lane & 15, kslot = lane >> 4, kgrp = kslot * 8;
  f32x4 acc1[2][4];
#pragma unroll
  for (int mt = 0; mt < 2; ++mt)
#pragma unroll
    for (int nt = 0; nt < 4; ++nt) acc1[mt][nt] = (f32x4){0.f, 0.f, 0.f, 0.f};
#pragma unroll 2
  for (int kk = 0; kk < 16; ++kk) {
    int k0 = kk * 32 + kgrp, swa = (mrow & 7) << 4;
    short8 a0 = *(const short8*)(smem + ((mrow * 1024 + k0 * 2) ^ swa));
    short8 a1 = *(const short8*)(smem + (((16 + mrow) * 1024 + k0 * 2) ^ swa));
#pragma unroll
    for (int nt = 0; nt < 4; ++nt) {
      short8 bw = load_wfrag(W1, k0, colbase + nt * 16 + mrow);
      acc1[0][nt] = __builtin_amdgcn_mfma_f32_16x16x32_bf16(a0, bw, acc1[0][nt], 0, 0, 0);
      acc1[1][nt] = __builtin_amdgcn_mfma_f32_16x16x32_bf16(a1, bw, acc1[1][nt], 0, 0, 0);
    }
  }
  float b1v[4];
#pragma unroll
  for (int nt = 0; nt < 4; ++nt) b1v[nt] = b1[colbase + nt * 16 + mrow];
  __syncthreads();
#pragma unroll
  for (int mt = 0; mt < 2; ++mt)
#pragma unroll
    for (int nt = 0; nt < 4; ++nt)
#pragma unroll
      for (int r = 0; r < 4; ++r) {
        float v = acc1[mt][nt][r] + b1v[nt];
        v = v / (1.f + __expf(-v));
        int row = mt * 16 + kslot * 4 + r, col = colbase + nt * 16 + mrow;
        *(short*)(smem + ((row * 512 + col * 2) ^ ((row & 7) << 4))) = f2bf(v);
      }
  __syncthreads();
  f32x4 acc2[2][4];
#pragma unroll
  for (int mt = 0; mt < 2; ++mt)
#pragma unroll
    for (int nt = 0; nt < 4; ++nt) acc2[mt][nt] = (f32x4){0.f, 0.f, 0.f, 0.f};
#pragma unroll 2
  for (int kk = 0; kk < 8; ++kk) {
    int k0 = kk * 32 + kgrp;
#pragma unroll
    for (int mt = 0; mt < 2; ++mt) {
      int arow = mt * 16 + mrow;
      short8 a = *(const short8*)(smem + ((arow * 512 + k0 * 2) ^ ((arow & 7) << 4)));
#pragma unroll
      for (int nt = 0; nt < 4; ++nt) {
        short8 bw = load_wfrag(W2, k0, colbase + nt * 16 + mrow);
        acc2[mt][nt] = __builtin_amdgcn_mfma_f32_16x16x32_bf16(a, bw, acc2[mt][nt], 0, 0, 0);
      }
    }
  }
#pragma unroll
  for (int mt = 0; mt < 2; ++mt)
#pragma unroll
    for (int nt = 0; nt < 4; ++nt) {
      int col = colbase + nt * 16 + mrow;
      float bv = b2[col];
#pragma unroll
      for (int r = 0; r < 4; ++r) {
        int row = mt * 16 + kslot * 4 + r, grow = r0 + row;
        if (grow < N) {
          size_t idx = (size_t)grow * 256 + col;
          h_out[idx] = acc2[mt][nt][r] + bv + hh[idx];
        }
      }
    }
}

extern "C" void kernel_launch(void* const* d_in, const int* in_sizes, int n_in,
                              void* d_out, int out_size, void* d_ws, size_t ws_size,
                              hipStream_t stream) {
  const float* x     = (const float*)d_in[0];
  const float* trans = (const float*)d_in[1];
  const float* edge  = (const float*)d_in[2];
  const float* hh    = (const float*)d_in[3];
  const float* W1    = (const float*)d_in[4];
  const float* b1    = (const float*)d_in[5];
  const float* W2    = (const float*)d_in[6];
  const float* b2    = (const float*)d_in[7];

  int N = in_sizes[0] / 3;
  float* coord_out = (float*)d_out;
  float* h_out = coord_out + (size_t)N * 3;
  int grid = (N + 31) / 32;

  if (ws_size >= WB_BYTES) {
    short* wb = (short*)d_ws;
    convw<<<(W1E + W2E) / 256, 256, 0, stream>>>(W1, W2, wb);
    agg_fused5<<<grid, 256, 0, stream>>>(x, trans, edge, hh, b1, b2, wb,
                                         coord_out, h_out, N);
  } else {
    agg_fallback<<<grid, 256, 0, stream>>>(x, trans, edge, hh, W1, b1, W2, b2,
                                           coord_out, h_out, N);
  }
}